// Round 5
// baseline (256.557 us; speedup 1.0000x reference)
//
#include <hip/hip_runtime.h>

typedef unsigned short u16;
typedef __bf16 bf16x8 __attribute__((ext_vector_type(8)));
typedef float f32x4 __attribute__((ext_vector_type(4)));
typedef unsigned short us8 __attribute__((ext_vector_type(8)));

__device__ inline u16 f2bf(float f) {
    union { float f; unsigned u; } v; v.f = f;
    unsigned r = v.u + 0x7FFFu + ((v.u >> 16) & 1u);
    return (u16)(r >> 16);
}
__device__ inline float bf2f(u16 h) {
    union { unsigned u; float f; } v; v.u = ((unsigned)h) << 16;
    return v.f;
}
__device__ inline f32x4 mfma16(bf16x8 a, bf16x8 b, f32x4 c) {
    return __builtin_amdgcn_mfma_f32_16x16x32_bf16(a, b, c, 0, 0, 0);
}
__device__ inline void gload_lds16(const u16* g, u16* l) {
    __builtin_amdgcn_global_load_lds(
        (const __attribute__((address_space(1))) void*)g,
        (__attribute__((address_space(3))) void*)l, 16, 0, 0);
}
union frag_cast { us8 u; bf16x8 b; };

// ---------------------------------------------------------------------------
// One-shot pack: x, Wq, Wk, Wv, Wo -> bf16; bias concat; YaRN sincos table
// ---------------------------------------------------------------------------
__global__ __launch_bounds__(256)
void pack_all(const float* __restrict__ x,  const float* __restrict__ Wq,
              const float* __restrict__ Wk, const float* __restrict__ Wv,
              const float* __restrict__ Wo, const float* __restrict__ bq,
              const float* __restrict__ bk, const float* __restrict__ bv,
              u16* __restrict__ xb, u16* __restrict__ Wqkvb,
              u16* __restrict__ Wob, float* __restrict__ bqkv,
              float2* __restrict__ tab)
{
    int blk = blockIdx.x;
    if (blk >= 9217) {                       // sincos table: 512 blocks
        int idx = (blk - 9217) * 256 + threadIdx.x;   // = pos*32 + d
        int d = idx & 31, pos = idx >> 5;
        float ex = (float)d * (1.0f / 32.0f);
        float freq = powf(10000.0f, -ex);
        float wl = 6.2831853071795864f / freq;
        float tt = fminf(fmaxf((wl - 32.0f) * (1.0f / 992.0f), 0.0f), 1.0f);
        float eff = (freq * (1.0f - tt) + 0.25f * freq * tt) * 1.1386294361119891f;
        float ang = (float)pos * eff;
        tab[idx] = make_float2(cosf(ang), sinf(ang));
        return;
    }
    if (blk == 9216) {
        for (int k = threadIdx.x; k < 3072; k += 256) {
            float v;
            if (k < 2048) v = bq[k];
            else if (k < 2560) v = bk[k - 2048];
            else v = bv[k - 2560];
            bqkv[k] = v;
        }
        return;
    }
    const float* src; u16* dst; size_t off;
    if (blk < 4096)      { src = x;  dst = xb;                 off = (size_t)blk * 2048; }
    else if (blk < 6144) { src = Wq; dst = Wqkvb;              off = (size_t)(blk - 4096) * 2048; }
    else if (blk < 6656) { src = Wk; dst = Wqkvb + 4194304;    off = (size_t)(blk - 6144) * 2048; }
    else if (blk < 7168) { src = Wv; dst = Wqkvb + 5242880;    off = (size_t)(blk - 6656) * 2048; }
    else                 { src = Wo; dst = Wob;                off = (size_t)(blk - 7168) * 2048; }
    size_t i = off + (size_t)threadIdx.x * 8;
    float4 v0 = *(const float4*)(src + i);
    float4 v1 = *(const float4*)(src + i + 4);
    us8 w;
    w[0] = f2bf(v0.x); w[1] = f2bf(v0.y); w[2] = f2bf(v0.z); w[3] = f2bf(v0.w);
    w[4] = f2bf(v1.x); w[5] = f2bf(v1.y); w[6] = f2bf(v1.z); w[7] = f2bf(v1.w);
    *(us8*)(dst + i) = w;
}

// ---------------------------------------------------------------------------
// 8-phase-family GEMM (m201 schedule ported): Y = A[M,K]*B[N,K]^T + bias.
//
// BM=256, BN=32*WNF (192 QKV / 128 out-proj), BK=64. 8 waves (4M x 2N),
// per-wave 64 x 16*WNF.  LDS: 2 buf x (A[2ks][256][32] + B[2ks][BN][32]).
// 4 phases per K-tile: (ks0,nh0)(ks0,nh1)(ks1,nh0)(ks1,nh1).  Each phase:
//   [ds_reads 3..7] [stage part] [s_barrier] [lgkmcnt(0)+sched_barrier]
//   [setprio(1) MFMA setprio(0)] [s_barrier]
// Overlap mechanism: small per-phase read batches; after the pre-MFMA
// barrier each wave waits only on ITS OWN few reads -> staggered MFMA
// starts while the LDS pipe services the remaining waves (the m201 62%
// mechanism; round-4's batched reads produced zero overlap).
// Counted-vmcnt ledger (loads/thread/tile = S0+S1, in-order retirement):
//   P3 tail: vmcnt(S1)=3  -> publishes STAGE0(t+1) for P0's ks0 reads,
//            leaves STAGE1(t+1) in flight.
//   P1 tail: vmcnt(S0)    -> publishes STAGE1(t) for P2's ks1 reads,
//            leaves STAGE0(t+1) in flight.   (QKV S0=4, out-proj S0=3)
//   vmcnt(0) only on the last tile.  Publication barriers are preceded by
//   the "memory"-clobbered vmcnt asm (reads after cannot be hoisted above).
// Write-after-read safety: STAGE0(t+1) (first overwrite of buf[(t+1)&1],
// last read in tile t-1) is issued in P1(t), which every wave reaches only
// after the P3(t-1) barrier, and each wave's tile-(t-1) ds_reads completed
// at its own P3(t-1) lgkmcnt(0) before that barrier.
// STAGE0/STAGE1 addressing + swizzle pair (colsw source / csw read):
// round-3 verbatim (passed correctness twice, 0 bank conflicts).
// ---------------------------------------------------------------------------
template<int WNF, int S0V, int OUT_BF16>
__global__ __launch_bounds__(512, 2)
void gemm_p4(const u16* __restrict__ A, const u16* __restrict__ B,
             const float* __restrict__ bias, void* __restrict__ Yv,
             int M, int N, int K)
{
    constexpr int BN = 32 * WNF;             // 192 or 128
    constexpr int BSL = BN * 32;             // B k-slice u16 (6144 / 4096)
    constexpr int ABUF = 16384;              // A region u16 (2 slices x 8192)
    constexpr int BUFU = ABUF + 2 * BSL;     // 28672 / 24576 u16
    constexpr int NH = WNF / 2;              // 3 or 2
    __shared__ u16 lds[2 * BUFU];            // 112 KB / 96 KB

    const int tid = threadIdx.x;
    const int lane = tid & 63;
    const int w = tid >> 6;                  // wave 0..7
    const int wr = w >> 1, wc = w & 1;       // 4M x 2N wave grid
    const int wg = blockIdx.x;               // bijective XCD swizzle (256 wg)
    const int swz = (wg & 7) * 32 + (wg >> 3);
    const int by = swz >> 4, bx = swz & 15;
    const long m0 = (long)by * 256;
    const long n0 = (long)bx * BN;
    const int cc = lane & 15, qq = lane >> 4;
    const int csw = (qq ^ ((cc >> 1) & 3)) << 3;

    const int sr = lane >> 2;
    const int colsw = ((lane & 3) ^ ((lane >> 3) & 3)) << 3;
    const u16* Ag = A + (m0 + sr) * (long)K + colsw;
    const u16* Bg = B + (n0 + sr) * (long)K + colsw;

    const int NT = K >> 6;                   // 64-wide K-tiles

    auto STAGE0 = [&](int u) {               // ks0 data (+B ks1 head on QKV)
        u16* buf = &lds[(u & 1) * BUFU];
        const long k0 = (long)u * 64;
        gload_lds16(Ag + (size_t)(w * 16) * K + k0,       buf + (w * 16) * 32);
        gload_lds16(Ag + (size_t)(128 + w * 16) * K + k0, buf + (128 + w * 16) * 32);
        gload_lds16(Bg + (size_t)(w * 16) * K + k0,       buf + ABUF + (w * 16) * 32);
        if (WNF == 6) {
            if (w < 4)
                gload_lds16(Bg + (size_t)(128 + w * 16) * K + k0,
                            buf + ABUF + (128 + w * 16) * 32);
            else
                gload_lds16(Bg + (size_t)((w - 4) * 16) * K + k0 + 32,
                            buf + ABUF + BSL + ((w - 4) * 16) * 32);
        }
    };
    auto STAGE1 = [&](int u) {               // ks1 remainder
        u16* buf = &lds[(u & 1) * BUFU];
        const long k0 = (long)u * 64 + 32;
        gload_lds16(Ag + (size_t)(w * 16) * K + k0,       buf + 8192 + (w * 16) * 32);
        gload_lds16(Ag + (size_t)(128 + w * 16) * K + k0, buf + 8192 + (128 + w * 16) * 32);
        if (WNF == 6)
            gload_lds16(Bg + (size_t)((w + 4) * 16) * K + k0,
                        buf + ABUF + BSL + ((w + 4) * 16) * 32);
        else
            gload_lds16(Bg + (size_t)(w * 16) * K + k0,
                        buf + ABUF + BSL + (w * 16) * 32);
    };

    f32x4 acc[4][WNF];
#pragma unroll
    for (int m = 0; m < 4; ++m)
#pragma unroll
        for (int n = 0; n < WNF; ++n) acc[m][n] = (f32x4){0.f, 0.f, 0.f, 0.f};

    STAGE0(0);
    STAGE1(0);
    asm volatile("s_waitcnt vmcnt(3)" ::: "memory");   // publish STAGE0(0)
    __builtin_amdgcn_s_barrier();
    __builtin_amdgcn_sched_barrier(0);

    for (int t = 0; t < NT; ++t) {
        const u16* buf = &lds[(t & 1) * BUFU];
        const u16* Ab0 = buf;
        const u16* Ab1 = buf + 8192;
        const u16* Bb0 = buf + ABUF;
        const u16* Bb1 = buf + ABUF + BSL;
        bf16x8 a[4], b0[NH], b1[NH];

        // ================= P0: (ks0, nh0) =================
#pragma unroll
        for (int m = 0; m < 4; ++m)
            a[m] = *(const bf16x8*)&Ab0[(wr * 64 + m * 16 + cc) * 32 + csw];
#pragma unroll
        for (int n = 0; n < NH; ++n)
            b0[n] = *(const bf16x8*)&Bb0[(wc * (16 * WNF) + n * 16 + cc) * 32 + csw];
        __builtin_amdgcn_s_barrier();
        asm volatile("s_waitcnt lgkmcnt(0)" ::: "memory");
        __builtin_amdgcn_sched_barrier(0);
        __builtin_amdgcn_s_setprio(1);
#pragma unroll
        for (int m = 0; m < 4; ++m)
#pragma unroll
            for (int n = 0; n < NH; ++n)
                acc[m][n] = mfma16(a[m], b0[n], acc[m][n]);
        __builtin_amdgcn_s_setprio(0);
        __builtin_amdgcn_s_barrier();

        // ================= P1: (ks0, nh1) =================
#pragma unroll
        for (int n = 0; n < NH; ++n)
            b1[n] = *(const bf16x8*)&Bb0[(wc * (16 * WNF) + (NH + n) * 16 + cc) * 32 + csw];
        if (t + 1 < NT) STAGE0(t + 1);
        __builtin_amdgcn_s_barrier();
        asm volatile("s_waitcnt lgkmcnt(0)" ::: "memory");
        __builtin_amdgcn_sched_barrier(0);
        __builtin_amdgcn_s_setprio(1);
#pragma unroll
        for (int m = 0; m < 4; ++m)
#pragma unroll
            for (int n = 0; n < NH; ++n)
                acc[m][NH + n] = mfma16(a[m], b1[n], acc[m][NH + n]);
        __builtin_amdgcn_s_setprio(0);
        if (t + 1 < NT) {
            if constexpr (S0V == 4) asm volatile("s_waitcnt vmcnt(4)" ::: "memory");
            else                    asm volatile("s_waitcnt vmcnt(3)" ::: "memory");
        } else {
            asm volatile("s_waitcnt vmcnt(0)" ::: "memory");
        }
        __builtin_amdgcn_s_barrier();                  // publish STAGE1(t)
        __builtin_amdgcn_sched_barrier(0);

        // ================= P2: (ks1, nh0) =================
#pragma unroll
        for (int m = 0; m < 4; ++m)
            a[m] = *(const bf16x8*)&Ab1[(wr * 64 + m * 16 + cc) * 32 + csw];
#pragma unroll
        for (int n = 0; n < NH; ++n)
            b0[n] = *(const bf16x8*)&Bb1[(wc * (16 * WNF) + n * 16 + cc) * 32 + csw];
        __builtin_amdgcn_s_barrier();
        asm volatile("s_waitcnt lgkmcnt(0)" ::: "memory");
        __builtin_amdgcn_sched_barrier(0);
        __builtin_amdgcn_s_setprio(1);
#pragma unroll
        for (int m = 0; m < 4; ++m)
#pragma unroll
            for (int n = 0; n < NH; ++n)
                acc[m][n] = mfma16(a[m], b0[n], acc[m][n]);
        __builtin_amdgcn_s_setprio(0);
        __builtin_amdgcn_s_barrier();

        // ================= P3: (ks1, nh1) =================
#pragma unroll
        for (int n = 0; n < NH; ++n)
            b1[n] = *(const bf16x8*)&Bb1[(wc * (16 * WNF) + (NH + n) * 16 + cc) * 32 + csw];
        if (t + 1 < NT) STAGE1(t + 1);
        __builtin_amdgcn_s_barrier();
        asm volatile("s_waitcnt lgkmcnt(0)" ::: "memory");
        __builtin_amdgcn_sched_barrier(0);
        __builtin_amdgcn_s_setprio(1);
#pragma unroll
        for (int m = 0; m < 4; ++m)
#pragma unroll
            for (int n = 0; n < NH; ++n)
                acc[m][NH + n] = mfma16(a[m], b1[n], acc[m][NH + n]);
        __builtin_amdgcn_s_setprio(0);
        if (t + 1 < NT) asm volatile("s_waitcnt vmcnt(3)" ::: "memory");
        else            asm volatile("s_waitcnt vmcnt(0)" ::: "memory");
        __builtin_amdgcn_s_barrier();                  // publish STAGE0(t+1)
        __builtin_amdgcn_sched_barrier(0);
    }

    // epilogue (proven C/D mapping)
#pragma unroll
    for (int m = 0; m < 4; ++m) {
#pragma unroll
        for (int n = 0; n < WNF; ++n) {
            long row = m0 + wr * 64 + m * 16 + qq * 4;
            long col = n0 + wc * (16 * WNF) + n * 16 + cc;
            float bvv = bias[col];
#pragma unroll
            for (int r2 = 0; r2 < 4; ++r2) {
                float v = acc[m][n][r2] + bvv;
                if (OUT_BF16)
                    ((u16*)Yv)[(row + r2) * (long)N + col] = f2bf(v);
                else
                    ((float*)Yv)[(row + r2) * (long)N + col] = v;
            }
        }
    }
}

// ---------------------------------------------------------------------------
// V: bf16 [B*S, 3072] (cols 2560..3071) -> bf16 transposed [B*NKV, 64, S]
// (proven kernel, verbatim)
// ---------------------------------------------------------------------------
__global__ __launch_bounds__(256)
void v_transpose(const u16* __restrict__ Vt, u16* __restrict__ VbT)
{
    __shared__ u16 tile[64][66];
    int s0 = blockIdx.x * 64;
    int bkv = blockIdx.y;
    int b = bkv >> 3, kv = bkv & 7;
    int t = threadIdx.x;
#pragma unroll
    for (int it = 0; it < 16; ++it) {
        int idx = t + it * 256;
        int s = idx >> 6, d = idx & 63;
        tile[s][d] = Vt[((size_t)(b * 2048 + s0 + s)) * 3072 + 2560 + kv * 64 + d];
    }
    __syncthreads();
#pragma unroll
    for (int it = 0; it < 16; ++it) {
        int idx = t + it * 256;
        int d = idx >> 6, s = idx & 63;
        VbT[((size_t)(bkv * 64 + d)) * 2048 + s0 + s] = tile[s][d];
    }
}

// ---------------------------------------------------------------------------
// Sliding-window attention with fused RoPE.  (proven kernel, verbatim)
// ---------------------------------------------------------------------------
__global__ __launch_bounds__(256, 2)
void attn_win2(const u16* __restrict__ QKVr, const u16* __restrict__ VbT,
               const float2* __restrict__ tab, const int* __restrict__ pid,
               const float* __restrict__ sinks, u16* __restrict__ Ctx)
{
    __shared__ u16 Ks[192 * 72];
    __shared__ u16 Vs[64 * 200];
    __shared__ u16 Pb[4 * 16 * 200];
    const int S = 2048;
    const int tid = threadIdx.x;
    const int lane = tid & 63;
    const int w = tid >> 6;
    const int cc = lane & 15, qq = lane >> 4;
    const int blk = blockIdx.x;
    const int qt = blk & 31;
    const int bkv = blk >> 5;
    const int b = bkv >> 3, kv = bkv & 7;
    const int q0 = qt * 64;
    const int ks0 = q0 - 128;
    const int h = kv * 4 + w;

    {
        const int kcol = 2048 + kv * 64;
#pragma unroll
        for (int it = 0; it < 3; ++it) {
            int c = tid + it * 256;
            int kk = c >> 2, dlo = (c & 3) << 3;
            int sk = ks0 + kk;
            us8 lo = {0, 0, 0, 0, 0, 0, 0, 0};
            us8 hi = {0, 0, 0, 0, 0, 0, 0, 0};
            if (sk >= 0) {
                size_t rowoff = (size_t)(b * S + sk) * 3072 + kcol;
                us8 li = *(const us8*)(QKVr + rowoff + dlo);
                us8 hiQ = *(const us8*)(QKVr + rowoff + dlo + 32);
                int pos = pid[b * S + sk];
                const float2* tp = tab + pos * 32 + dlo;
#pragma unroll
                for (int jj = 0; jj < 8; ++jj) {
                    float2 cs = tp[jj];
                    float x1 = bf2f(li[jj]), x2 = bf2f(hiQ[jj]);
                    lo[jj] = f2bf(x1 * cs.x - x2 * cs.y);
                    hi[jj] = f2bf(x2 * cs.x + x1 * cs.y);
                }
            }
            *(us8*)&Ks[kk * 72 + dlo] = lo;
            *(us8*)&Ks[kk * 72 + dlo + 32] = hi;
        }
    }
    const u16* VtBase = VbT + (size_t)bkv * 64 * S;
#pragma unroll
    for (int it = 0; it < 6; ++it) {
        int c = tid + it * 256;
        int d = c / 24, kc = c % 24;
        int kk0 = kc << 3;
        int sk = ks0 + kk0;
        us8 v = {0, 0, 0, 0, 0, 0, 0, 0};
        if (sk >= 0) v = *(const us8*)(VtBase + (size_t)d * S + sk);
        *(us8*)&Vs[d * 200 + kk0] = v;
    }
    __syncthreads();

    const float sinkv = sinks[h];
    u16* Pw = &Pb[w * 3200];

    for (int i = 0; i < 4; ++i) {
        int m = b * S + q0 + i * 16 + cc;
        const u16* Qrow = QKVr + (size_t)m * 3072 + h * 64;
        us8 qlo = *(const us8*)(Qrow + qq * 8);
        us8 qhi = *(const us8*)(Qrow + 32 + qq * 8);
        int pos = pid[m];
        const float2* tp = tab + pos * 32 + qq * 8;
        frag_cast a0, a1;
#pragma unroll
        for (int jj = 0; jj < 8; ++jj) {
            float2 cs = tp[jj];
            float x1 = bf2f(qlo[jj]), x2 = bf2f(qhi[jj]);
            a0.u[jj] = f2bf(x1 * cs.x - x2 * cs.y);
            a1.u[jj] = f2bf(x2 * cs.x + x1 * cs.y);
        }
        bf16x8 aq0 = a0.b, aq1 = a1.b;

        f32x4 sc[12];
#pragma unroll
        for (int j = 0; j < 12; j++) sc[j] = (f32x4){0.f, 0.f, 0.f, 0.f};
#pragma unroll
        for (int j = 0; j < 12; j++) {
            bf16x8 b0 = *(const bf16x8*)&Ks[(j * 16 + cc) * 72 + qq * 8];
            bf16x8 b1 = *(const bf16x8*)&Ks[(j * 16 + cc) * 72 + 32 + qq * 8];
            sc[j] = mfma16(aq0, b0, sc[j]);
            sc[j] = mfma16(aq1, b1, sc[j]);
        }

#pragma unroll
        for (int r = 0; r < 4; ++r) {
            int qi = i * 16 + qq * 4 + r;
            float sval[12];
            float mx = -3.0e38f;
#pragma unroll
            for (int j = 0; j < 12; j++) {
                int kk = j * 16 + cc;
                float s = sc[j][r] * 0.125f;
                bool ok = (kk > qi) && (kk <= qi + 128) && (ks0 + kk >= 0);
                s = ok ? s : -3.0e38f;
                sval[j] = s;
                mx = fmaxf(mx, s);
            }
#pragma unroll
            for (int off = 1; off < 16; off <<= 1) mx = fmaxf(mx, __shfl_xor(mx, off));
            mx = fmaxf(mx, sinkv);
            float sum = 0.f;
#pragma unroll
            for (int j = 0; j < 12; j++) {
                float p = __expf(sval[j] - mx);
                sval[j] = p;
                sum += p;
            }
#pragma unroll
            for (int off = 1; off < 16; off <<= 1) sum += __shfl_xor(sum, off);
            float rden = 1.0f / (sum + __expf(sinkv - mx));
#pragma unroll
            for (int j = 0; j < 12; j++)
                Pw[(qq * 4 + r) * 200 + j * 16 + cc] = f2bf(sval[j] * rden);
        }

        f32x4 o[4];
#pragma unroll
        for (int jt = 0; jt < 4; jt++) o[jt] = (f32x4){0.f, 0.f, 0.f, 0.f};
#pragma unroll
        for (int ks = 0; ks < 6; ks++) {
            bf16x8 ap = *(const bf16x8*)&Pw[cc * 200 + ks * 32 + qq * 8];
#pragma unroll
            for (int jt = 0; jt < 4; jt++) {
                bf16x8 bv = *(const bf16x8*)&Vs[(jt * 16 + cc) * 200 + ks * 32 + qq * 8];
                o[jt] = mfma16(ap, bv, o[jt]);
            }
        }
#pragma unroll
        for (int jt = 0; jt < 4; jt++) {
#pragma unroll
            for (int r = 0; r < 4; r++) {
                size_t off = ((size_t)(b * S + q0 + i * 16 + qq * 4 + r)) * 2048
                           + h * 64 + jt * 16 + cc;
                Ctx[off] = f2bf(o[jt][r]);
            }
        }
    }
}

// ---------------------------------------------------------------------------
extern "C" void kernel_launch(void* const* d_in, const int* in_sizes, int n_in,
                              void* d_out, int out_size, void* d_ws, size_t ws_size,
                              hipStream_t stream)
{
    const float* x    = (const float*)d_in[0];
    const float* Wq   = (const float*)d_in[1];
    const float* bq   = (const float*)d_in[2];
    const float* Wk   = (const float*)d_in[3];
    const float* bk   = (const float*)d_in[4];
    const float* Wv   = (const float*)d_in[5];
    const float* bv   = (const float*)d_in[6];
    const float* Wo   = (const float*)d_in[7];
    const float* bo   = (const float*)d_in[8];
    const float* sinks = (const float*)d_in[9];
    const int*   pid  = (const int*)d_in[10];
    float* out = (float*)d_out;

    char*  ws    = (char*)d_ws;
    u16*   Wqkvb = (u16*)ws;                         // 12,582,912 B
    u16*   Wob   = (u16*)(ws + 12582912);            //  8,388,608 B
    u16*   xb    = (u16*)(ws + 20971520);            // 16,777,216 B (then Ctx)
    u16*   Ctx   = xb;
    u16*   QKVr  = (u16*)(ws + 37748736);            // 25,165,824 B
    u16*   VbT   = (u16*)(ws + 62914560);            //  4,194,304 B
    float* bqkv  = (float*)(ws + 67108864);          //     12,288 B
    float2* tab  = (float2*)(ws + 67121152);         //  1,048,576 B

    pack_all<<<9729, 256, 0, stream>>>(x, Wq, Wk, Wv, Wo, bq, bk, bv,
                                       xb, Wqkvb, Wob, bqkv, tab);

    // QKV: 256x192 tiles, 16x16 = 256 blocks (1/CU), 4-phase schedule
    gemm_p4<6, 4, 1><<<256, 512, 0, stream>>>(xb, Wqkvb, bqkv, QKVr,
                                              4096, 3072, 2048);

    v_transpose<<<dim3(32, 16), 256, 0, stream>>>(QKVr, VbT);

    attn_win2<<<512, 256, 0, stream>>>(QKVr, VbT, tab, pid, sinks, Ctx);

    // out-proj: 256x128 tiles, 16x16 = 256 blocks
    gemm_p4<4, 3, 0><<<256, 512, 0, stream>>>(Ctx, Wob, bo, out,
                                              4096, 2048, 2048);
}

// Round 6
// 245.045 us; speedup vs baseline: 1.0470x; 1.0470x over previous
//
#include <hip/hip_runtime.h>

typedef unsigned short u16;
typedef __bf16 bf16x8 __attribute__((ext_vector_type(8)));
typedef float f32x4 __attribute__((ext_vector_type(4)));
typedef unsigned short us8 __attribute__((ext_vector_type(8)));

__device__ inline u16 f2bf(float f) {
    union { float f; unsigned u; } v; v.f = f;
    unsigned r = v.u + 0x7FFFu + ((v.u >> 16) & 1u);
    return (u16)(r >> 16);
}
__device__ inline float bf2f(u16 h) {
    union { unsigned u; float f; } v; v.u = ((unsigned)h) << 16;
    return v.f;
}
__device__ inline f32x4 mfma16(bf16x8 a, bf16x8 b, f32x4 c) {
    return __builtin_amdgcn_mfma_f32_16x16x32_bf16(a, b, c, 0, 0, 0);
}
__device__ inline void gload_lds16(const u16* g, u16* l) {
    __builtin_amdgcn_global_load_lds(
        (const __attribute__((address_space(1))) void*)g,
        (__attribute__((address_space(3))) void*)l, 16, 0, 0);
}
union frag_cast { us8 u; bf16x8 b; };

// ---------------------------------------------------------------------------
// One-shot pack: x, Wq, Wk, Wv, Wo -> bf16; bias concat; YaRN sincos table
// ---------------------------------------------------------------------------
__global__ __launch_bounds__(256)
void pack_all(const float* __restrict__ x,  const float* __restrict__ Wq,
              const float* __restrict__ Wk, const float* __restrict__ Wv,
              const float* __restrict__ Wo, const float* __restrict__ bq,
              const float* __restrict__ bk, const float* __restrict__ bv,
              u16* __restrict__ xb, u16* __restrict__ Wqkvb,
              u16* __restrict__ Wob, float* __restrict__ bqkv,
              float2* __restrict__ tab)
{
    int blk = blockIdx.x;
    if (blk >= 9217) {                       // sincos table: 512 blocks
        int idx = (blk - 9217) * 256 + threadIdx.x;   // = pos*32 + d
        int d = idx & 31, pos = idx >> 5;
        float ex = (float)d * (1.0f / 32.0f);
        float freq = powf(10000.0f, -ex);
        float wl = 6.2831853071795864f / freq;
        float tt = fminf(fmaxf((wl - 32.0f) * (1.0f / 992.0f), 0.0f), 1.0f);
        float eff = (freq * (1.0f - tt) + 0.25f * freq * tt) * 1.1386294361119891f;
        float ang = (float)pos * eff;
        tab[idx] = make_float2(cosf(ang), sinf(ang));
        return;
    }
    if (blk == 9216) {
        for (int k = threadIdx.x; k < 3072; k += 256) {
            float v;
            if (k < 2048) v = bq[k];
            else if (k < 2560) v = bk[k - 2048];
            else v = bv[k - 2560];
            bqkv[k] = v;
        }
        return;
    }
    const float* src; u16* dst; size_t off;
    if (blk < 4096)      { src = x;  dst = xb;                 off = (size_t)blk * 2048; }
    else if (blk < 6144) { src = Wq; dst = Wqkvb;              off = (size_t)(blk - 4096) * 2048; }
    else if (blk < 6656) { src = Wk; dst = Wqkvb + 4194304;    off = (size_t)(blk - 6144) * 2048; }
    else if (blk < 7168) { src = Wv; dst = Wqkvb + 5242880;    off = (size_t)(blk - 6656) * 2048; }
    else                 { src = Wo; dst = Wob;                off = (size_t)(blk - 7168) * 2048; }
    size_t i = off + (size_t)threadIdx.x * 8;
    float4 v0 = *(const float4*)(src + i);
    float4 v1 = *(const float4*)(src + i + 4);
    us8 w;
    w[0] = f2bf(v0.x); w[1] = f2bf(v0.y); w[2] = f2bf(v0.z); w[3] = f2bf(v0.w);
    w[4] = f2bf(v1.x); w[5] = f2bf(v1.y); w[6] = f2bf(v1.z); w[7] = f2bf(v1.w);
    *(us8*)(dst + i) = w;
}

// ---------------------------------------------------------------------------
// Late-stage GEMM (round-3 structure, ONE change: STAGE issued AFTER the
// MFMA cluster):  Y[M,N] = A[M,K]*B[N,K]^T + bias[N].
//
// BM=256, BN=32*WNF (192 QKV / 128 out-proj), BK=64. 8 waves (4M x 2N).
// LDS: 2 buffers x (A[2ks][256][32] + B[2ks][BN][32]).  Per K-tile, 2
// ks-blocks, each:
//   vmcnt(counted) ; s_barrier ; ds_read frags(ks) ; sched_barrier ;
//   setprio(1) MFMA setprio(0) ; sched_barrier ; STAGE part of tile t+1
// WHY stage-after-MFMA (the r3->r6 A/B variable): r3's stage was issued at
// the block top; its vmem returns (~200-900cy later) landed inside the NEXT
// block's read-drain window, and the 56KB of gload-LDS writes pushed every
// wave's lgkm completion back ~500+cy (r3 measured fully serial: 4058
// cyc/tile = MFMA 1862 + reads 1880 + stage 550).  Issuing stage after the
// MFMA cluster makes its returns land during an MFMA window (LDS pipe idle),
// preserving the per-wave read-stagger overlap the compiler's lgkm waits
// provide.
// Counted-vmcnt ledger (in-order retirement; slots/tile = S0+S1):
//   ks0(t): outstanding = S0(t)+S1(t) (both issued in tile t-1's block
//           tails) -> vmcnt(S1)=3 drains exactly STAGE0(t).
//   ks1(t): outstanding = S1(t)+S0(t+1) -> vmcnt(S0V) drains STAGE1(t).
//   QKV S0=4,S1=3; out-proj 3,3.  vmcnt(0) only on the last tile.
// WAR safety: STAGE0(t+1) (first overwrite of buf[(t+1)&1]) is issued after
// the ks0(t) barrier; any wave's reads of that region (ks0(t-1)) were
// lgkm-consumed by its own MFMA(ks0,t-1) before it arrived at the ks1(t-1)
// barrier -- two barriers before any STAGE0(t+1) issue.
// Swizzle pair (colsw source / csw read) byte-identical to rounds 1-5
// (verified correct, 0 bank conflicts).
// ---------------------------------------------------------------------------
template<int WNF, int S0V, int OUT_BF16>
__global__ __launch_bounds__(512, 2)
void gemm_ls(const u16* __restrict__ A, const u16* __restrict__ B,
             const float* __restrict__ bias, void* __restrict__ Yv,
             int M, int N, int K)
{
    constexpr int BN = 32 * WNF;             // 192 or 128
    constexpr int BSL = BN * 32;             // B k-slice u16 (6144 / 4096)
    constexpr int ABUF = 16384;              // A region u16 (2 slices x 8192)
    constexpr int BUFU = ABUF + 2 * BSL;     // 28672 / 24576 u16
    __shared__ u16 lds[2 * BUFU];            // 112 KB / 96 KB

    const int tid = threadIdx.x;
    const int lane = tid & 63;
    const int w = tid >> 6;                  // wave 0..7
    const int wr = w >> 1, wc = w & 1;       // 4M x 2N wave grid
    const int wg = blockIdx.x;               // bijective XCD swizzle (256 wg)
    const int swz = (wg & 7) * 32 + (wg >> 3);
    const int by = swz >> 4, bx = swz & 15;
    const long m0 = (long)by * 256;
    const long n0 = (long)bx * BN;
    const int cc = lane & 15, qq = lane >> 4;
    const int csw = (qq ^ ((cc >> 1) & 3)) << 3;

    const int sr = lane >> 2;
    const int colsw = ((lane & 3) ^ ((lane >> 3) & 3)) << 3;
    const u16* Ag = A + (m0 + sr) * (long)K + colsw;
    const u16* Bg = B + (n0 + sr) * (long)K + colsw;

    const int NT = K >> 6;                   // 64-wide K-tiles

    auto STAGE0 = [&](int u) {               // ks0 data (+B ks1 head on QKV)
        u16* buf = &lds[(u & 1) * BUFU];
        const long k0 = (long)u * 64;
        gload_lds16(Ag + (size_t)(w * 16) * K + k0,       buf + (w * 16) * 32);
        gload_lds16(Ag + (size_t)(128 + w * 16) * K + k0, buf + (128 + w * 16) * 32);
        gload_lds16(Bg + (size_t)(w * 16) * K + k0,       buf + ABUF + (w * 16) * 32);
        if (WNF == 6) {
            if (w < 4)
                gload_lds16(Bg + (size_t)(128 + w * 16) * K + k0,
                            buf + ABUF + (128 + w * 16) * 32);
            else
                gload_lds16(Bg + (size_t)((w - 4) * 16) * K + k0 + 32,
                            buf + ABUF + BSL + ((w - 4) * 16) * 32);
        }
    };
    auto STAGE1 = [&](int u) {               // ks1 remainder
        u16* buf = &lds[(u & 1) * BUFU];
        const long k0 = (long)u * 64 + 32;
        gload_lds16(Ag + (size_t)(w * 16) * K + k0,       buf + 8192 + (w * 16) * 32);
        gload_lds16(Ag + (size_t)(128 + w * 16) * K + k0, buf + 8192 + (128 + w * 16) * 32);
        if (WNF == 6)
            gload_lds16(Bg + (size_t)((w + 4) * 16) * K + k0,
                        buf + ABUF + BSL + ((w + 4) * 16) * 32);
        else
            gload_lds16(Bg + (size_t)(w * 16) * K + k0,
                        buf + ABUF + BSL + (w * 16) * 32);
    };

    f32x4 acc[4][WNF];
#pragma unroll
    for (int m = 0; m < 4; ++m)
#pragma unroll
        for (int n = 0; n < WNF; ++n) acc[m][n] = (f32x4){0.f, 0.f, 0.f, 0.f};

    STAGE0(0);
    STAGE1(0);

    for (int t = 0; t < NT; ++t) {
        const u16* buf = &lds[(t & 1) * BUFU];

        // ================= ks-block 0 =================
        asm volatile("s_waitcnt vmcnt(3)" ::: "memory");   // STAGE0(t) landed
        __builtin_amdgcn_s_barrier();
        __builtin_amdgcn_sched_barrier(0);
        {
            const u16* Ab = buf;
            const u16* Bb = buf + ABUF;
            bf16x8 af[4], bfr[WNF];
#pragma unroll
            for (int n = 0; n < WNF; ++n)
                bfr[n] = *(const bf16x8*)&Bb[(wc * (16 * WNF) + n * 16 + cc) * 32 + csw];
#pragma unroll
            for (int m = 0; m < 4; ++m)
                af[m] = *(const bf16x8*)&Ab[(wr * 64 + m * 16 + cc) * 32 + csw];
            __builtin_amdgcn_sched_barrier(0);
            __builtin_amdgcn_s_setprio(1);
#pragma unroll
            for (int m = 0; m < 4; ++m)
#pragma unroll
                for (int n = 0; n < WNF; ++n)
                    acc[m][n] = mfma16(af[m], bfr[n], acc[m][n]);
            __builtin_amdgcn_s_setprio(0);
            __builtin_amdgcn_sched_barrier(0);
            if (t + 1 < NT) STAGE0(t + 1);     // LATE issue: returns land in
            __builtin_amdgcn_sched_barrier(0); // an MFMA window, not a drain
        }

        // ================= ks-block 1 =================
        if (t + 1 < NT) {
            if constexpr (S0V == 4) asm volatile("s_waitcnt vmcnt(4)" ::: "memory");
            else                    asm volatile("s_waitcnt vmcnt(3)" ::: "memory");
        } else {
            asm volatile("s_waitcnt vmcnt(0)" ::: "memory");
        }
        __builtin_amdgcn_s_barrier();
        __builtin_amdgcn_sched_barrier(0);
        {
            const u16* Ab = buf + 8192;
            const u16* Bb = buf + ABUF + BSL;
            bf16x8 af[4], bfr[WNF];
#pragma unroll
            for (int n = 0; n < WNF; ++n)
                bfr[n] = *(const bf16x8*)&Bb[(wc * (16 * WNF) + n * 16 + cc) * 32 + csw];
#pragma unroll
            for (int m = 0; m < 4; ++m)
                af[m] = *(const bf16x8*)&Ab[(wr * 64 + m * 16 + cc) * 32 + csw];
            __builtin_amdgcn_sched_barrier(0);
            __builtin_amdgcn_s_setprio(1);
#pragma unroll
            for (int m = 0; m < 4; ++m)
#pragma unroll
                for (int n = 0; n < WNF; ++n)
                    acc[m][n] = mfma16(af[m], bfr[n], acc[m][n]);
            __builtin_amdgcn_s_setprio(0);
            __builtin_amdgcn_sched_barrier(0);
            if (t + 1 < NT) STAGE1(t + 1);
            __builtin_amdgcn_sched_barrier(0);
        }
    }

    // epilogue (proven C/D mapping)
#pragma unroll
    for (int m = 0; m < 4; ++m) {
#pragma unroll
        for (int n = 0; n < WNF; ++n) {
            long row = m0 + wr * 64 + m * 16 + qq * 4;
            long col = n0 + wc * (16 * WNF) + n * 16 + cc;
            float bvv = bias[col];
#pragma unroll
            for (int r2 = 0; r2 < 4; ++r2) {
                float v = acc[m][n][r2] + bvv;
                if (OUT_BF16)
                    ((u16*)Yv)[(row + r2) * (long)N + col] = f2bf(v);
                else
                    ((float*)Yv)[(row + r2) * (long)N + col] = v;
            }
        }
    }
}

// ---------------------------------------------------------------------------
// V: bf16 [B*S, 3072] (cols 2560..3071) -> bf16 transposed [B*NKV, 64, S]
// (proven kernel, verbatim)
// ---------------------------------------------------------------------------
__global__ __launch_bounds__(256)
void v_transpose(const u16* __restrict__ Vt, u16* __restrict__ VbT)
{
    __shared__ u16 tile[64][66];
    int s0 = blockIdx.x * 64;
    int bkv = blockIdx.y;
    int b = bkv >> 3, kv = bkv & 7;
    int t = threadIdx.x;
#pragma unroll
    for (int it = 0; it < 16; ++it) {
        int idx = t + it * 256;
        int s = idx >> 6, d = idx & 63;
        tile[s][d] = Vt[((size_t)(b * 2048 + s0 + s)) * 3072 + 2560 + kv * 64 + d];
    }
    __syncthreads();
#pragma unroll
    for (int it = 0; it < 16; ++it) {
        int idx = t + it * 256;
        int d = idx >> 6, s = idx & 63;
        VbT[((size_t)(bkv * 64 + d)) * 2048 + s0 + s] = tile[s][d];
    }
}

// ---------------------------------------------------------------------------
// Sliding-window attention with fused RoPE.  (proven kernel, verbatim)
// ---------------------------------------------------------------------------
__global__ __launch_bounds__(256, 2)
void attn_win2(const u16* __restrict__ QKVr, const u16* __restrict__ VbT,
               const float2* __restrict__ tab, const int* __restrict__ pid,
               const float* __restrict__ sinks, u16* __restrict__ Ctx)
{
    __shared__ u16 Ks[192 * 72];
    __shared__ u16 Vs[64 * 200];
    __shared__ u16 Pb[4 * 16 * 200];
    const int S = 2048;
    const int tid = threadIdx.x;
    const int lane = tid & 63;
    const int w = tid >> 6;
    const int cc = lane & 15, qq = lane >> 4;
    const int blk = blockIdx.x;
    const int qt = blk & 31;
    const int bkv = blk >> 5;
    const int b = bkv >> 3, kv = bkv & 7;
    const int q0 = qt * 64;
    const int ks0 = q0 - 128;
    const int h = kv * 4 + w;

    {
        const int kcol = 2048 + kv * 64;
#pragma unroll
        for (int it = 0; it < 3; ++it) {
            int c = tid + it * 256;
            int kk = c >> 2, dlo = (c & 3) << 3;
            int sk = ks0 + kk;
            us8 lo = {0, 0, 0, 0, 0, 0, 0, 0};
            us8 hi = {0, 0, 0, 0, 0, 0, 0, 0};
            if (sk >= 0) {
                size_t rowoff = (size_t)(b * S + sk) * 3072 + kcol;
                us8 li = *(const us8*)(QKVr + rowoff + dlo);
                us8 hiQ = *(const us8*)(QKVr + rowoff + dlo + 32);
                int pos = pid[b * S + sk];
                const float2* tp = tab + pos * 32 + dlo;
#pragma unroll
                for (int jj = 0; jj < 8; ++jj) {
                    float2 cs = tp[jj];
                    float x1 = bf2f(li[jj]), x2 = bf2f(hiQ[jj]);
                    lo[jj] = f2bf(x1 * cs.x - x2 * cs.y);
                    hi[jj] = f2bf(x2 * cs.x + x1 * cs.y);
                }
            }
            *(us8*)&Ks[kk * 72 + dlo] = lo;
            *(us8*)&Ks[kk * 72 + dlo + 32] = hi;
        }
    }
    const u16* VtBase = VbT + (size_t)bkv * 64 * S;
#pragma unroll
    for (int it = 0; it < 6; ++it) {
        int c = tid + it * 256;
        int d = c / 24, kc = c % 24;
        int kk0 = kc << 3;
        int sk = ks0 + kk0;
        us8 v = {0, 0, 0, 0, 0, 0, 0, 0};
        if (sk >= 0) v = *(const us8*)(VtBase + (size_t)d * S + sk);
        *(us8*)&Vs[d * 200 + kk0] = v;
    }
    __syncthreads();

    const float sinkv = sinks[h];
    u16* Pw = &Pb[w * 3200];

    for (int i = 0; i < 4; ++i) {
        int m = b * S + q0 + i * 16 + cc;
        const u16* Qrow = QKVr + (size_t)m * 3072 + h * 64;
        us8 qlo = *(const us8*)(Qrow + qq * 8);
        us8 qhi = *(const us8*)(Qrow + 32 + qq * 8);
        int pos = pid[m];
        const float2* tp = tab + pos * 32 + qq * 8;
        frag_cast a0, a1;
#pragma unroll
        for (int jj = 0; jj < 8; ++jj) {
            float2 cs = tp[jj];
            float x1 = bf2f(qlo[jj]), x2 = bf2f(qhi[jj]);
            a0.u[jj] = f2bf(x1 * cs.x - x2 * cs.y);
            a1.u[jj] = f2bf(x2 * cs.x + x1 * cs.y);
        }
        bf16x8 aq0 = a0.b, aq1 = a1.b;

        f32x4 sc[12];
#pragma unroll
        for (int j = 0; j < 12; j++) sc[j] = (f32x4){0.f, 0.f, 0.f, 0.f};
#pragma unroll
        for (int j = 0; j < 12; j++) {
            bf16x8 b0 = *(const bf16x8*)&Ks[(j * 16 + cc) * 72 + qq * 8];
            bf16x8 b1 = *(const bf16x8*)&Ks[(j * 16 + cc) * 72 + 32 + qq * 8];
            sc[j] = mfma16(aq0, b0, sc[j]);
            sc[j] = mfma16(aq1, b1, sc[j]);
        }

#pragma unroll
        for (int r = 0; r < 4; ++r) {
            int qi = i * 16 + qq * 4 + r;
            float sval[12];
            float mx = -3.0e38f;
#pragma unroll
            for (int j = 0; j < 12; j++) {
                int kk = j * 16 + cc;
                float s = sc[j][r] * 0.125f;
                bool ok = (kk > qi) && (kk <= qi + 128) && (ks0 + kk >= 0);
                s = ok ? s : -3.0e38f;
                sval[j] = s;
                mx = fmaxf(mx, s);
            }
#pragma unroll
            for (int off = 1; off < 16; off <<= 1) mx = fmaxf(mx, __shfl_xor(mx, off));
            mx = fmaxf(mx, sinkv);
            float sum = 0.f;
#pragma unroll
            for (int j = 0; j < 12; j++) {
                float p = __expf(sval[j] - mx);
                sval[j] = p;
                sum += p;
            }
#pragma unroll
            for (int off = 1; off < 16; off <<= 1) sum += __shfl_xor(sum, off);
            float rden = 1.0f / (sum + __expf(sinkv - mx));
#pragma unroll
            for (int j = 0; j < 12; j++)
                Pw[(qq * 4 + r) * 200 + j * 16 + cc] = f2bf(sval[j] * rden);
        }

        f32x4 o[4];
#pragma unroll
        for (int jt = 0; jt < 4; jt++) o[jt] = (f32x4){0.f, 0.f, 0.f, 0.f};
#pragma unroll
        for (int ks = 0; ks < 6; ks++) {
            bf16x8 ap = *(const bf16x8*)&Pw[cc * 200 + ks * 32 + qq * 8];
#pragma unroll
            for (int jt = 0; jt < 4; jt++) {
                bf16x8 bv = *(const bf16x8*)&Vs[(jt * 16 + cc) * 200 + ks * 32 + qq * 8];
                o[jt] = mfma16(ap, bv, o[jt]);
            }
        }
#pragma unroll
        for (int jt = 0; jt < 4; jt++) {
#pragma unroll
            for (int r = 0; r < 4; r++) {
                size_t off = ((size_t)(b * S + q0 + i * 16 + qq * 4 + r)) * 2048
                           + h * 64 + jt * 16 + cc;
                Ctx[off] = f2bf(o[jt][r]);
            }
        }
    }
}

// ---------------------------------------------------------------------------
extern "C" void kernel_launch(void* const* d_in, const int* in_sizes, int n_in,
                              void* d_out, int out_size, void* d_ws, size_t ws_size,
                              hipStream_t stream)
{
    const float* x    = (const float*)d_in[0];
    const float* Wq   = (const float*)d_in[1];
    const float* bq   = (const float*)d_in[2];
    const float* Wk   = (const float*)d_in[3];
    const float* bk   = (const float*)d_in[4];
    const float* Wv   = (const float*)d_in[5];
    const float* bv   = (const float*)d_in[6];
    const float* Wo   = (const float*)d_in[7];
    const float* bo   = (const float*)d_in[8];
    const float* sinks = (const float*)d_in[9];
    const int*   pid  = (const int*)d_in[10];
    float* out = (float*)d_out;

    char*  ws    = (char*)d_ws;
    u16*   Wqkvb = (u16*)ws;                         // 12,582,912 B
    u16*   Wob   = (u16*)(ws + 12582912);            //  8,388,608 B
    u16*   xb    = (u16*)(ws + 20971520);            // 16,777,216 B (then Ctx)
    u16*   Ctx   = xb;
    u16*   QKVr  = (u16*)(ws + 37748736);            // 25,165,824 B
    u16*   VbT   = (u16*)(ws + 62914560);            //  4,194,304 B
    float* bqkv  = (float*)(ws + 67108864);          //     12,288 B
    float2* tab  = (float2*)(ws + 67121152);         //  1,048,576 B

    pack_all<<<9729, 256, 0, stream>>>(x, Wq, Wk, Wv, Wo, bq, bk, bv,
                                       xb, Wqkvb, Wob, bqkv, tab);

    // QKV: 256x192 tiles, 16x16 = 256 blocks (1/CU), late-stage schedule
    gemm_ls<6, 4, 1><<<256, 512, 0, stream>>>(xb, Wqkvb, bqkv, QKVr,
                                              4096, 3072, 2048);

    v_transpose<<<dim3(32, 16), 256, 0, stream>>>(QKVr, VbT);

    attn_win2<<<512, 256, 0, stream>>>(QKVr, VbT, tab, pid, sinks, Ctx);

    // out-proj: 256x128 tiles, 16x16 = 256 blocks
    gemm_ls<4, 3, 0><<<256, 512, 0, stream>>>(Ctx, Wob, bo, out,
                                              4096, 2048, 2048);
}